// Round 2
// baseline (2726.409 us; speedup 1.0000x reference)
//
#include <hip/hip_runtime.h>
#include <cstdint>

using u16 = unsigned short;
using u32 = uint32_t;

typedef __bf16 bf16x8 __attribute__((ext_vector_type(8)));
typedef float  f32x4  __attribute__((ext_vector_type(4)));
typedef u32    uvec4  __attribute__((ext_vector_type(4)));

// ---------------- numeric helpers ----------------
static __device__ __forceinline__ u16 f2bf(float x) {
  u32 u = __float_as_uint(x);
  u32 r = (u + 0x7FFFu + ((u >> 16) & 1u)) >> 16;   // RNE
  return (u16)r;
}

static __device__ __forceinline__ u32 rotl32(u32 v, int s) {
  return (v << s) | (v >> (32 - s));
}

// JAX threefry2x32 (20 rounds), matches jax._src.prng exactly.
static __device__ __forceinline__ void threefry2x32(u32 k0, u32 k1, u32 x0, u32 x1,
                                                    u32& o0, u32& o1) {
  u32 k2 = k0 ^ k1 ^ 0x1BD11BDAu;
  x0 += k0; x1 += k1;
  x0 += x1; x1 = rotl32(x1, 13); x1 ^= x0;
  x0 += x1; x1 = rotl32(x1, 15); x1 ^= x0;
  x0 += x1; x1 = rotl32(x1, 26); x1 ^= x0;
  x0 += x1; x1 = rotl32(x1, 6);  x1 ^= x0;
  x0 += k1; x1 += k2 + 1u;
  x0 += x1; x1 = rotl32(x1, 17); x1 ^= x0;
  x0 += x1; x1 = rotl32(x1, 29); x1 ^= x0;
  x0 += x1; x1 = rotl32(x1, 16); x1 ^= x0;
  x0 += x1; x1 = rotl32(x1, 24); x1 ^= x0;
  x0 += k2; x1 += k0 + 2u;
  x0 += x1; x1 = rotl32(x1, 13); x1 ^= x0;
  x0 += x1; x1 = rotl32(x1, 15); x1 ^= x0;
  x0 += x1; x1 = rotl32(x1, 26); x1 ^= x0;
  x0 += x1; x1 = rotl32(x1, 6);  x1 ^= x0;
  x0 += k0; x1 += k1 + 3u;
  x0 += x1; x1 = rotl32(x1, 17); x1 ^= x0;
  x0 += x1; x1 = rotl32(x1, 29); x1 ^= x0;
  x0 += x1; x1 = rotl32(x1, 16); x1 ^= x0;
  x0 += x1; x1 = rotl32(x1, 24); x1 ^= x0;
  x0 += k1; x1 += k2 + 4u;
  x0 += x1; x1 = rotl32(x1, 13); x1 ^= x0;
  x0 += x1; x1 = rotl32(x1, 15); x1 ^= x0;
  x0 += x1; x1 = rotl32(x1, 26); x1 ^= x0;
  x0 += x1; x1 = rotl32(x1, 6);  x1 ^= x0;
  x0 += k2; x1 += k0 + 5u;
  o0 = x0; o1 = x1;
}

// bits -> N(0,1) exactly like jax.random.normal(f32): u = uniform(nextafter(-1,0), 1),
// z = sqrt(2) * erfinv(u)  (XLA/Giles f32 erfinv polynomial).
static __device__ __forceinline__ float bits_to_normal(u32 bits) {
  const float lo = __uint_as_float(0xBF7FFFFFu);          // nextafter(-1, 0)
  float f = __uint_as_float((bits >> 9) | 0x3F800000u) - 1.0f;  // [0,1)
  float x = fmaxf(lo, f * 2.0f + lo);                     // (hi-lo) rounds to 2.0f
  float w = -logf((1.0f - x) * (1.0f + x));
  float p;
  if (w < 5.0f) {
    w -= 2.5f;
    p = 2.81022636e-08f;
    p = fmaf(p, w, 3.43273939e-07f);
    p = fmaf(p, w, -3.5233877e-06f);
    p = fmaf(p, w, -4.39150654e-06f);
    p = fmaf(p, w, 0.00021858087f);
    p = fmaf(p, w, -0.00125372503f);
    p = fmaf(p, w, -0.00417768164f);
    p = fmaf(p, w, 0.246640727f);
    p = fmaf(p, w, 1.50140941f);
  } else {
    w = sqrtf(w) - 3.0f;
    p = -0.000200214257f;
    p = fmaf(p, w, 0.000100950558f);
    p = fmaf(p, w, 0.00134934322f);
    p = fmaf(p, w, -0.00367342844f);
    p = fmaf(p, w, 0.00573950773f);
    p = fmaf(p, w, -0.0076224613f);
    p = fmaf(p, w, 0.00943887047f);
    p = fmaf(p, w, 1.00167406f);
    p = fmaf(p, w, 2.83297682f);
  }
  return 1.41421356f * p * x;
}

// ---------------- S1: pack weights (transpose + f32->bf16) ----------------
// W1 (4097,1024): first 4096 rows -> W1T (1024,4096) bf16
// W2 (1024,4096)                  -> W2T (4096,1024) bf16
__global__ __launch_bounds__(256) void s1_pack(
    const float* __restrict__ W1f, const float* __restrict__ W1g,
    const float* __restrict__ W2f, const float* __restrict__ W2g,
    u16* __restrict__ W1fT, u16* __restrict__ W1gT,
    u16* __restrict__ W2fT, u16* __restrict__ W2gT) {
  __shared__ float tile[64][65];
  const int z = blockIdx.z;
  const float* in = (z == 0) ? W1f : (z == 1) ? W1g : (z == 2) ? W2f : W2g;
  u16* out = (z == 0) ? W1fT : (z == 1) ? W1gT : (z == 2) ? W2fT : W2gT;
  const int R = (z < 2) ? 4096 : 1024;
  const int C = (z < 2) ? 1024 : 4096;
  const int rt = (z < 2) ? blockIdx.x : blockIdx.y;
  const int ct = (z < 2) ? blockIdx.y : blockIdx.x;
  const int r0 = rt * 64, c0 = ct * 64;
  const int tix = threadIdx.x;
  #pragma unroll
  for (int i = 0; i < 16; ++i) {
    int lin = i * 256 + tix;
    int row = lin >> 6, col = lin & 63;
    tile[row][col] = in[(size_t)(r0 + row) * C + c0 + col];
  }
  __syncthreads();
  #pragma unroll
  for (int i = 0; i < 16; ++i) {
    int lin = i * 256 + tix;
    int orow = lin >> 6, ocol = lin & 63;
    out[(size_t)(c0 + orow) * R + r0 + ocol] = f2bf(tile[ocol][orow]);
  }
}

// ---------------- S2: init state, t=0 output, step keys ----------------
// JAX >= 0.4.36: threefry_partitionable defaults ON.
// split(key(42), 63) [foldlike]: key_t = threefry((0,42), x0=0, x1=t) -> (y0, y1)
__global__ __launch_bounds__(256) void s2_init(
    const float* __restrict__ A0, float* __restrict__ A, u16* __restrict__ Abf,
    float* __restrict__ out, uint2* __restrict__ keys) {
  const int bid = blockIdx.x, tix = threadIdx.x;
  if (bid == 1024) {
    if (tix < 63) {
      u32 y0, y1;
      threefry2x32(0u, 42u, 0u, (u32)tix, y0, y1);
      keys[tix] = make_uint2(y0, y1);
    }
    return;
  }
  const int e = bid * 256 + tix;            // 0..262143 over (b, n)
  const int b = e >> 12, n = e & 4095;
  const float a0 = A0[e];
  const float sig = (n % 65 == 0) ? 0.0f : 1.0f / (1.0f + expf(-a0));
  const u16 ab = f2bf(a0);
  #pragma unroll
  for (int s = 0; s < 4; ++s) {
    size_t m = (size_t)s * 64 + b;
    A[m * 4096 + n] = a0;
    Abf[m * 4096 + n] = ab;
    out[((size_t)s * 4096 + b) * 4096 + n] = sig;   // (s, t=0, b, :)
  }
}

// ---------------- G1: H = tanh(Abf @ W1T^T + b1 + t*w1_last), + dW gen ----------------
// GEMM blocks: 256 = 8 m-tiles(32) x 16 n-tiles(64) x 2 (f,g). dW blocks: 64.
__global__ __launch_bounds__(256) void g1_hidden(
    const u16* __restrict__ Abf, const u16* __restrict__ W1fT, const u16* __restrict__ W1gT,
    u16* __restrict__ Hf, u16* __restrict__ Hg,
    const float* __restrict__ b1f, const float* __restrict__ b1g,
    const float* __restrict__ W1fv, const float* __restrict__ W1gv,
    const float* __restrict__ tarr, const uint2* __restrict__ keys,
    float* __restrict__ dWbuf, int step) {
  const int bid = blockIdx.x;
  const int tix = threadIdx.x;
  if (bid >= 256) {
    // dW: partitionable random_bits — element e: counter (0, e), bits = y0 ^ y1
    const int d = bid - 256;
    const uint2 key = keys[step];
    const float sdt = sqrtf(tarr[1] - tarr[0]);
    #pragma unroll
    for (int i = 0; i < 16; ++i) {
      u32 e = (u32)d * 4096u + (u32)i * 256u + (u32)tix;
      u32 y0, y1;
      threefry2x32(key.x, key.y, 0u, e, y0, y1);
      dWbuf[e] = bits_to_normal(y0 ^ y1) * sdt;
    }
    return;
  }
  const int mt = bid & 7, nt = (bid >> 3) & 15, fg = bid >> 7;
  const int m0 = mt * 32, n0 = nt * 64;
  const u16* W = fg ? W1gT : W1fT;
  __shared__ __align__(16) u16 lA[32 * 64];
  __shared__ __align__(16) u16 lB[64 * 64];
  const int wid = tix >> 6, lane = tix & 63;
  // staging map: thread -> (row = tix>>3, 16B slot = tix&7), XOR-swizzled LDS
  const int srow = tix >> 3, sc = tix & 7;
  const u32 swz = (u32)((sc * 16) ^ ((srow & 7) << 4));
  const u32 wa = (u32)srow * 128 + swz;
  const u32 wb1 = (u32)(srow + 32) * 128 + swz;   // (srow+32)&7 == srow&7
  const u16* gA = Abf + (size_t)(m0 + srow) * 4096 + sc * 8;
  const u16* gB0 = W + (size_t)(n0 + srow) * 4096 + sc * 8;
  const u16* gB1 = gB0 + (size_t)32 * 4096;
  // mfma fragment addresses (wave tile 16x32)
  const int wm = (wid >> 1) * 16, wn = (wid & 1) * 32;
  const int lr = lane & 15, lk = (lane >> 4) * 8;
  const int tra = wm + lr;
  const u32 abyte = (u32)tra * 128 + ((u32)(lk * 2) ^ ((u32)(tra & 7) << 4));
  const int trb0 = wn + lr, trb1 = trb0 + 16;
  const u32 bbyte0 = (u32)trb0 * 128 + ((u32)(lk * 2) ^ ((u32)(trb0 & 7) << 4));
  const u32 bbyte1 = (u32)trb1 * 128 + ((u32)(lk * 2) ^ ((u32)(trb1 & 7) << 4));
  f32x4 acc0 = {0.f, 0.f, 0.f, 0.f};
  f32x4 acc1 = {0.f, 0.f, 0.f, 0.f};
  uvec4 ra = *(const uvec4*)gA;
  uvec4 rb0 = *(const uvec4*)gB0;
  uvec4 rb1 = *(const uvec4*)gB1;
  for (int it = 0; it < 64; ++it) {
    __syncthreads();
    *(uvec4*)((char*)lA + wa) = ra;
    *(uvec4*)((char*)lB + wa) = rb0;
    *(uvec4*)((char*)lB + wb1) = rb1;
    if (it + 1 < 64) {
      gA += 64; gB0 += 64; gB1 += 64;
      ra = *(const uvec4*)gA; rb0 = *(const uvec4*)gB0; rb1 = *(const uvec4*)gB1;
    }
    __syncthreads();
    bf16x8 av0 = *(const bf16x8*)((char*)lA + abyte);
    bf16x8 av1 = *(const bf16x8*)((char*)lA + (abyte ^ 64u));
    bf16x8 b00 = *(const bf16x8*)((char*)lB + bbyte0);
    bf16x8 b01 = *(const bf16x8*)((char*)lB + (bbyte0 ^ 64u));
    bf16x8 b10 = *(const bf16x8*)((char*)lB + bbyte1);
    bf16x8 b11 = *(const bf16x8*)((char*)lB + (bbyte1 ^ 64u));
    acc0 = __builtin_amdgcn_mfma_f32_16x16x32_bf16(av0, b00, acc0, 0, 0, 0);
    acc1 = __builtin_amdgcn_mfma_f32_16x16x32_bf16(av0, b10, acc1, 0, 0, 0);
    acc0 = __builtin_amdgcn_mfma_f32_16x16x32_bf16(av1, b01, acc0, 0, 0, 0);
    acc1 = __builtin_amdgcn_mfma_f32_16x16x32_bf16(av1, b11, acc1, 0, 0, 0);
  }
  // epilogue: + b1[n] + t*W1[4096][n], tanh, -> bf16 H
  const float tprev = tarr[step];
  const float* b1 = fg ? b1g : b1f;
  const float* w1last = (fg ? W1gv : W1fv) + (size_t)4096 * 1024;
  u16* H = fg ? Hg : Hf;
  const int ncol0 = n0 + wn + lr;
  const int ncol1 = ncol0 + 16;
  const float c10 = b1[ncol0] + tprev * w1last[ncol0];
  const float c11 = b1[ncol1] + tprev * w1last[ncol1];
  const int mrow = m0 + wm + (lane >> 4) * 4;
  #pragma unroll
  for (int r = 0; r < 4; ++r) {
    H[(size_t)(mrow + r) * 1024 + ncol0] = f2bf(tanhf(acc0[r] + c10));
    H[(size_t)(mrow + r) * 1024 + ncol1] = f2bf(tanhf(acc1[r] + c11));
  }
}

// ---------------- G2: drift/diff GEMMs + SDE update + output ----------------
static __device__ __forceinline__ void gemm64_pass(
    const u16* __restrict__ HA, const u16* __restrict__ WB,
    int m0, int n0, int tix, u16* lA, u16* lB,
    u32 wst0, u32 wst1, u32 ab0, u32 ab1, u32 bb0, u32 bb1,
    f32x4& a00, f32x4& a01, f32x4& a10, f32x4& a11) {
  const int srow = tix >> 3, sc = tix & 7;
  const u16* gA0 = HA + (size_t)(m0 + srow) * 1024 + sc * 8;
  const u16* gA1 = gA0 + 32 * 1024;
  const u16* gB0 = WB + (size_t)(n0 + srow) * 1024 + sc * 8;
  const u16* gB1 = gB0 + 32 * 1024;
  uvec4 r0 = *(const uvec4*)gA0;
  uvec4 r1 = *(const uvec4*)gA1;
  uvec4 r2 = *(const uvec4*)gB0;
  uvec4 r3 = *(const uvec4*)gB1;
  for (int it = 0; it < 16; ++it) {
    __syncthreads();
    *(uvec4*)((char*)lA + wst0) = r0;
    *(uvec4*)((char*)lA + wst1) = r1;
    *(uvec4*)((char*)lB + wst0) = r2;
    *(uvec4*)((char*)lB + wst1) = r3;
    if (it + 1 < 16) {
      gA0 += 64; gA1 += 64; gB0 += 64; gB1 += 64;
      r0 = *(const uvec4*)gA0; r1 = *(const uvec4*)gA1;
      r2 = *(const uvec4*)gB0; r3 = *(const uvec4*)gB1;
    }
    __syncthreads();
    #pragma unroll
    for (int kx = 0; kx < 2; ++kx) {
      const u32 x = (u32)kx * 64u;
      bf16x8 a0 = *(const bf16x8*)((char*)lA + (ab0 ^ x));
      bf16x8 a1 = *(const bf16x8*)((char*)lA + (ab1 ^ x));
      bf16x8 b0 = *(const bf16x8*)((char*)lB + (bb0 ^ x));
      bf16x8 b1 = *(const bf16x8*)((char*)lB + (bb1 ^ x));
      a00 = __builtin_amdgcn_mfma_f32_16x16x32_bf16(a0, b0, a00, 0, 0, 0);
      a01 = __builtin_amdgcn_mfma_f32_16x16x32_bf16(a0, b1, a01, 0, 0, 0);
      a10 = __builtin_amdgcn_mfma_f32_16x16x32_bf16(a1, b0, a10, 0, 0, 0);
      a11 = __builtin_amdgcn_mfma_f32_16x16x32_bf16(a1, b1, a11, 0, 0, 0);
    }
  }
}

static __device__ __forceinline__ void g2_epi(
    f32x4 df, f32x4 dg, int mbase, int ncol, float dt,
    const float* __restrict__ b2f, const float* __restrict__ b2g,
    float* __restrict__ A, u16* __restrict__ Abf,
    const float* __restrict__ dWbuf, float* __restrict__ out, int step) {
  const float bf_ = b2f[ncol], bg_ = b2g[ncol];
  #pragma unroll
  for (int r = 0; r < 4; ++r) {
    const int m = mbase + r;
    const float drift = df[r] + bf_;
    const float graw = dg[r] + bg_;
    const float diff = fmaxf(graw, 0.0f) + log1pf(expf(-fabsf(graw)));  // softplus
    const size_t ai = (size_t)m * 4096 + ncol;
    const float aprev = A[ai];
    const float dw = dWbuf[(size_t)(m & 63) * 4096 + ncol];
    const float anew = aprev + drift * dt + diff * dw;
    A[ai] = anew;
    Abf[ai] = f2bf(anew);
    const float sig = (ncol % 65 == 0) ? 0.0f : 1.0f / (1.0f + expf(-anew));
    out[((size_t)((m >> 6) * 64 + step + 1) * 64 + (m & 63)) * 4096 + ncol] = sig;
  }
}

__global__ __launch_bounds__(256) void g2_update(
    const u16* __restrict__ Hf, const u16* __restrict__ Hg,
    const u16* __restrict__ W2fT, const u16* __restrict__ W2gT,
    const float* __restrict__ b2f, const float* __restrict__ b2g,
    float* __restrict__ A, u16* __restrict__ Abf,
    const float* __restrict__ dWbuf, float* __restrict__ out,
    const float* __restrict__ tarr, int step) {
  const int bid = blockIdx.x, tix = threadIdx.x;
  const int mt = bid & 3, nt = bid >> 2;
  const int m0 = mt * 64, n0 = nt * 64;
  __shared__ __align__(16) u16 lA[64 * 64];
  __shared__ __align__(16) u16 lB[64 * 64];
  const int wid = tix >> 6, lane = tix & 63;
  const int wm = (wid >> 1) * 32, wn = (wid & 1) * 32;
  const int lr = lane & 15, lk = (lane >> 4) * 8;
  const int srow = tix >> 3, sc = tix & 7;
  const u32 swz = (u32)((sc * 16) ^ ((srow & 7) << 4));
  const u32 wst0 = (u32)srow * 128 + swz;
  const u32 wst1 = (u32)(srow + 32) * 128 + swz;
  const int tra0 = wm + lr, tra1 = tra0 + 16;
  const u32 ab0 = (u32)tra0 * 128 + ((u32)(lk * 2) ^ ((u32)(tra0 & 7) << 4));
  const u32 ab1 = (u32)tra1 * 128 + ((u32)(lk * 2) ^ ((u32)(tra1 & 7) << 4));
  const int trb0 = wn + lr, trb1 = trb0 + 16;
  const u32 bb0 = (u32)trb0 * 128 + ((u32)(lk * 2) ^ ((u32)(trb0 & 7) << 4));
  const u32 bb1 = (u32)trb1 * 128 + ((u32)(lk * 2) ^ ((u32)(trb1 & 7) << 4));
  f32x4 z = {0.f, 0.f, 0.f, 0.f};
  f32x4 f00 = z, f01 = z, f10 = z, f11 = z;
  f32x4 g00 = z, g01 = z, g10 = z, g11 = z;
  gemm64_pass(Hf, W2fT, m0, n0, tix, lA, lB, wst0, wst1, ab0, ab1, bb0, bb1, f00, f01, f10, f11);
  gemm64_pass(Hg, W2gT, m0, n0, tix, lA, lB, wst0, wst1, ab0, ab1, bb0, bb1, g00, g01, g10, g11);
  const float dt = tarr[1] - tarr[0];
  const int mb0 = m0 + wm + (lane >> 4) * 4;
  const int nc0 = n0 + wn + lr;
  g2_epi(f00, g00, mb0,      nc0,      dt, b2f, b2g, A, Abf, dWbuf, out, step);
  g2_epi(f01, g01, mb0,      nc0 + 16, dt, b2f, b2g, A, Abf, dWbuf, out, step);
  g2_epi(f10, g10, mb0 + 16, nc0,      dt, b2f, b2g, A, Abf, dWbuf, out, step);
  g2_epi(f11, g11, mb0 + 16, nc0 + 16, dt, b2f, b2g, A, Abf, dWbuf, out, step);
}

// ---------------- launch ----------------
extern "C" void kernel_launch(void* const* d_in, const int* in_sizes, int n_in,
                              void* d_out, int out_size, void* d_ws, size_t ws_size,
                              hipStream_t stream) {
  const float* A0 = (const float*)d_in[0];
  const float* tarr = (const float*)d_in[1];
  const float* W1f = (const float*)d_in[2];
  const float* b1f = (const float*)d_in[3];
  const float* W2f = (const float*)d_in[4];
  const float* b2f = (const float*)d_in[5];
  const float* W1g = (const float*)d_in[6];
  const float* b1g = (const float*)d_in[7];
  const float* W2g = (const float*)d_in[8];
  const float* b2g = (const float*)d_in[9];
  float* out = (float*)d_out;
  char* ws = (char*)d_ws;
  const size_t MB = 1024 * 1024;
  u16* W1fT = (u16*)(ws + 0 * MB);          // (1024,4096) bf16, 8 MB
  u16* W1gT = (u16*)(ws + 8 * MB);
  u16* W2fT = (u16*)(ws + 16 * MB);         // (4096,1024) bf16, 8 MB
  u16* W2gT = (u16*)(ws + 24 * MB);
  float* A  = (float*)(ws + 32 * MB);       // (256,4096) f32 state, 4 MB
  u16* Abf  = (u16*)(ws + 36 * MB);         // bf16 mirror, 2 MB
  u16* Hf   = (u16*)(ws + 38 * MB);         // (256,1024) bf16
  u16* Hg   = (u16*)(ws + 38 * MB + 512 * 1024);
  float* dW = (float*)(ws + 39 * MB);       // (64,4096) f32, 1 MB
  uint2* keys = (uint2*)(ws + 40 * MB);     // 63 step keys

  s1_pack<<<dim3(64, 16, 4), 256, 0, stream>>>(W1f, W1g, W2f, W2g, W1fT, W1gT, W2fT, W2gT);
  s2_init<<<dim3(1025), 256, 0, stream>>>(A0, A, Abf, out, keys);
  for (int i = 0; i < 63; ++i) {
    g1_hidden<<<dim3(320), 256, 0, stream>>>(Abf, W1fT, W1gT, Hf, Hg, b1f, b1g,
                                             W1f, W1g, tarr, keys, dW, i);
    g2_update<<<dim3(256), 256, 0, stream>>>(Hf, Hg, W2fT, W2gT, b2f, b2g,
                                             A, Abf, dW, out, tarr, i);
  }
}